// Round 5
// baseline (451.660 us; speedup 1.0000x reference)
//
#include <hip/hip_runtime.h>
#include <hip/hip_bf16.h>

// Problem constants (B,N,HC,HH,K,D) = (64,300,64,64,3,10)
#define BB 64
#define NN 300
#define HH 64
#define RTOT (BB*NN)          // 19200 rows
#define KIO  (3*HH*HH)        // 12288: weights_pool inner size per d
#define JOUT (HH*HH)          // 4096 output cols

typedef __attribute__((ext_vector_type(8))) _Float16 f16x8;
typedef __attribute__((ext_vector_type(4))) float floatx4;

__device__ inline float tanh_fast(float x) {
    float e = __expf(2.f * x);
    return 1.f - 2.f * __builtin_amdgcn_rcpf(e + 1.f);
}

// Fused preprocessing: block-role partitioned single dispatch.
//   [0,300)      adjacency: A[n,:] = softmax(relu(E[n]·E[:]))
//   [300,600)    in_proj: h = relu(z@Win^T + bin), 64-row tiles
//   [600,675)    node_bias: bN = E@bpool
//   [675,1699)   cvt_wout: Wout fp32->fp16
// (node_weights role ELIMINATED -- W_eff is built on the fly in k_node_mm)
__global__ __launch_bounds__(256) void k_pre(const float* __restrict__ E,
                                             const float* __restrict__ z,
                                             const float* __restrict__ Win,
                                             const float* __restrict__ bin,
                                             const float* __restrict__ Wout,
                                             const float* __restrict__ bpool,
                                             float* __restrict__ A,
                                             float* __restrict__ h,
                                             float* __restrict__ bN,
                                             _Float16* __restrict__ Wh) {
    __shared__ float smem[8576];
    int bid = blockIdx.x, tid = threadIdx.x;

    if (bid < 300) {
        // ---- adjacency ----
        float* sE  = smem;          // 16
        float* row = smem + 16;     // 300
        float* red = smem + 320;    // 256
        int n = bid;
        if (tid < 10) sE[tid] = E[n*10 + tid];
        __syncthreads();
        float lmax = -1e30f;
        for (int m = tid; m < NN; m += 256) {
            float s = 0.f;
            #pragma unroll
            for (int d = 0; d < 10; ++d) s += sE[d] * E[m*10 + d];
            s = fmaxf(s, 0.f);
            row[m] = s;
            lmax = fmaxf(lmax, s);
        }
        red[tid] = lmax; __syncthreads();
        for (int off = 128; off > 0; off >>= 1) {
            if (tid < off) red[tid] = fmaxf(red[tid], red[tid+off]);
            __syncthreads();
        }
        float mx = red[0]; __syncthreads();
        float lsum = 0.f;
        for (int m = tid; m < NN; m += 256) {
            float e = __expf(row[m] - mx);
            row[m] = e;
            lsum += e;
        }
        red[tid] = lsum; __syncthreads();
        for (int off = 128; off > 0; off >>= 1) {
            if (tid < off) red[tid] += red[tid+off];
            __syncthreads();
        }
        float inv = 1.f / red[0];
        for (int m = tid; m < NN; m += 256) A[n*NN + m] = row[m] * inv;
    } else if (bid < 600) {
        // ---- in_proj: 64r x 64o tile ----
        float* Wt = smem;           // 64*68
        float* zl = smem + 4352;    // 64*66
        int tx = tid & 15, ty = tid >> 4;
        int r0 = (bid - 300) * 64;
        for (int e = tid; e < 4096; e += 256) {
            int o = e >> 6, c = e & 63;
            Wt[c*68 + o] = Win[e];
            zl[o*66 + c] = z[(size_t)(r0 + o)*64 + c];
        }
        __syncthreads();
        float4 bo = *(const float4*)&bin[tx*4];
        float acc[4][4];
        #pragma unroll
        for (int s = 0; s < 4; ++s) { acc[s][0]=bo.x; acc[s][1]=bo.y; acc[s][2]=bo.z; acc[s][3]=bo.w; }
        const float* zr = &zl[(ty*4)*66];
        for (int c = 0; c < 64; ++c) {
            float4 w = *(const float4*)&Wt[c*68 + tx*4];
            float z0 = zr[c], z1 = zr[66+c], z2 = zr[132+c], z3 = zr[198+c];
            acc[0][0] += z0*w.x; acc[0][1] += z0*w.y; acc[0][2] += z0*w.z; acc[0][3] += z0*w.w;
            acc[1][0] += z1*w.x; acc[1][1] += z1*w.y; acc[1][2] += z1*w.z; acc[1][3] += z1*w.w;
            acc[2][0] += z2*w.x; acc[2][1] += z2*w.y; acc[2][2] += z2*w.z; acc[2][3] += z2*w.w;
            acc[3][0] += z3*w.x; acc[3][1] += z3*w.y; acc[3][2] += z3*w.z; acc[3][3] += z3*w.w;
        }
        #pragma unroll
        for (int s = 0; s < 4; ++s) {
            float4 v = make_float4(fmaxf(acc[s][0],0.f), fmaxf(acc[s][1],0.f),
                                   fmaxf(acc[s][2],0.f), fmaxf(acc[s][3],0.f));
            *(float4*)&h[(size_t)(r0 + ty*4 + s)*64 + tx*4] = v;
        }
    } else if (bid < 675) {
        // ---- node_bias ----
        int idx = (bid - 600)*256 + tid;   // < 19200
        int n = idx >> 6, o = idx & 63;
        float s = 0.f;
        #pragma unroll
        for (int d = 0; d < 10; ++d) s += E[n*10 + d] * bpool[d*64 + o];
        bN[idx] = s;
    } else {
        // ---- cvt_wout ----
        int idx = (bid - 675)*256 + tid;   // < 262144
        Wh[idx] = (_Float16)Wout[idx];
    }
}

// xg1[b,r,c] = sum_m A[r,m] h[b,m,c].
// Wave owns 5 rows of A for one b; lane = channel c. A chunks are
// wave-uniform float4 loads; each h load feeds 5 FMAs. Grid (15, 64).
__global__ __launch_bounds__(256) void k_spatialA(const float* __restrict__ A,
                                                  const float* __restrict__ h,
                                                  float* __restrict__ xg1) {
    int tid = threadIdx.x;
    int c = tid & 63;
    int w = __builtin_amdgcn_readfirstlane(tid >> 6);
    int b = blockIdx.y;
    int r0 = blockIdx.x * 20 + w * 5;                  // 0..295
    const float* S = A + (size_t)r0 * NN;
    const float* hb = h + (size_t)b * NN * 64 + c;
    float a0 = 0.f, a1 = 0.f, a2 = 0.f, a3 = 0.f, a4 = 0.f;
    for (int m = 0; m < NN; m += 4) {
        float4 s0 = *(const float4*)(S + 0*NN + m);
        float4 s1 = *(const float4*)(S + 1*NN + m);
        float4 s2 = *(const float4*)(S + 2*NN + m);
        float4 s3 = *(const float4*)(S + 3*NN + m);
        float4 s4 = *(const float4*)(S + 4*NN + m);
        float h0 = hb[(m+0)*64];
        float h1 = hb[(m+1)*64];
        float h2 = hb[(m+2)*64];
        float h3 = hb[(m+3)*64];
        a0 = fmaf(s0.x,h0,a0); a0 = fmaf(s0.y,h1,a0); a0 = fmaf(s0.z,h2,a0); a0 = fmaf(s0.w,h3,a0);
        a1 = fmaf(s1.x,h0,a1); a1 = fmaf(s1.y,h1,a1); a1 = fmaf(s1.z,h2,a1); a1 = fmaf(s1.w,h3,a1);
        a2 = fmaf(s2.x,h0,a2); a2 = fmaf(s2.y,h1,a2); a2 = fmaf(s2.z,h2,a2); a2 = fmaf(s2.w,h3,a2);
        a3 = fmaf(s3.x,h0,a3); a3 = fmaf(s3.y,h1,a3); a3 = fmaf(s3.z,h2,a3); a3 = fmaf(s3.w,h3,a3);
        a4 = fmaf(s4.x,h0,a4); a4 = fmaf(s4.y,h1,a4); a4 = fmaf(s4.z,h2,a4); a4 = fmaf(s4.w,h3,a4);
    }
    float* dst = xg1 + ((size_t)b * NN + r0) * 64 + c;
    dst[0*64] = a0; dst[1*64] = a1; dst[2*64] = a2; dst[3*64] = a3; dst[4*64] = a4;
}

// Chebyshev on features: xg2 = T2@h = (2A^2 - I)h = 2*A@xg1 - h
__global__ __launch_bounds__(256) void k_spatialB(const float* __restrict__ A,
                                                  const float* __restrict__ xg1,
                                                  const float* __restrict__ h,
                                                  float* __restrict__ xg2) {
    int tid = threadIdx.x;
    int c = tid & 63;
    int w = __builtin_amdgcn_readfirstlane(tid >> 6);
    int b = blockIdx.y;
    int r0 = blockIdx.x * 20 + w * 5;
    const float* S = A + (size_t)r0 * NN;
    const float* xb = xg1 + (size_t)b * NN * 64 + c;
    float a0 = 0.f, a1 = 0.f, a2 = 0.f, a3 = 0.f, a4 = 0.f;
    for (int m = 0; m < NN; m += 4) {
        float4 s0 = *(const float4*)(S + 0*NN + m);
        float4 s1 = *(const float4*)(S + 1*NN + m);
        float4 s2 = *(const float4*)(S + 2*NN + m);
        float4 s3 = *(const float4*)(S + 3*NN + m);
        float4 s4 = *(const float4*)(S + 4*NN + m);
        float x0 = xb[(m+0)*64];
        float x1 = xb[(m+1)*64];
        float x2 = xb[(m+2)*64];
        float x3 = xb[(m+3)*64];
        a0 = fmaf(s0.x,x0,a0); a0 = fmaf(s0.y,x1,a0); a0 = fmaf(s0.z,x2,a0); a0 = fmaf(s0.w,x3,a0);
        a1 = fmaf(s1.x,x0,a1); a1 = fmaf(s1.y,x1,a1); a1 = fmaf(s1.z,x2,a1); a1 = fmaf(s1.w,x3,a1);
        a2 = fmaf(s2.x,x0,a2); a2 = fmaf(s2.y,x1,a2); a2 = fmaf(s2.z,x2,a2); a2 = fmaf(s2.w,x3,a2);
        a3 = fmaf(s3.x,x0,a3); a3 = fmaf(s3.y,x1,a3); a3 = fmaf(s3.z,x2,a3); a3 = fmaf(s3.w,x3,a3);
        a4 = fmaf(s4.x,x0,a4); a4 = fmaf(s4.y,x1,a4); a4 = fmaf(s4.z,x2,a4); a4 = fmaf(s4.w,x3,a4);
    }
    const float* hb = h   + ((size_t)b * NN + r0) * 64 + c;
    float*       dst = xg2 + ((size_t)b * NN + r0) * 64 + c;
    dst[0*64] = 2.f*a0 - hb[0*64];
    dst[1*64] = 2.f*a1 - hb[1*64];
    dst[2*64] = 2.f*a2 - hb[2*64];
    dst[3*64] = 2.f*a3 - hb[3*64];
    dst[4*64] = 2.f*a4 - hb[4*64];
}

// h2[b,n,o] = bN[n,o] + sum_{ki} xg[b,n,ki] * W_eff[ki,o]
// where W_eff[ki,o] = sum_d E[n,d] * pool[d,ki,o] is built IN-KERNEL
// (pool is 491 KB, L2-resident; E[n,:] lands in SGPRs since n is uniform).
// This eliminates the Wn buffer: 14.75 MB HBM write + ~118 MB HBM re-read.
// Block = (n, 32 b's), grid (300,2). LDS 72 KB -> 2 blocks/CU.
// Inner loop identical to the proven R3 form; arithmetic bit-identical.
__global__ __launch_bounds__(256) void k_node_mm(const float* __restrict__ h,
                                                 const float* __restrict__ xg1,
                                                 const float* __restrict__ xg2,
                                                 const float* __restrict__ pool,
                                                 const float* __restrict__ E,
                                                 const float* __restrict__ bN,
                                                 _Float16* __restrict__ h2h) {
    __shared__ float Wnl[12288];    // 48 KB: W_eff[ki*64 + o]
    __shared__ float xgl[32][192];  // 24 KB
    int tid = threadIdx.x;
    int n = blockIdx.x, b0 = blockIdx.y * 32;

    // E[n,:] -> SGPRs (n uniform per block)
    float Ev[10];
    #pragma unroll
    for (int d = 0; d < 10; ++d) Ev[d] = E[n*10 + d];

    // Build W_eff panel: 3072 float4s, pool reads coalesced
    const float4* p4 = (const float4*)pool;
    for (int e4 = tid; e4 < 3072; e4 += 256) {
        float4 acc = make_float4(0.f, 0.f, 0.f, 0.f);
        #pragma unroll
        for (int d = 0; d < 10; ++d) {
            float4 pv = p4[d*3072 + e4];
            acc.x = fmaf(Ev[d], pv.x, acc.x);
            acc.y = fmaf(Ev[d], pv.y, acc.y);
            acc.z = fmaf(Ev[d], pv.z, acc.z);
            acc.w = fmaf(Ev[d], pv.w, acc.w);
        }
        ((float4*)Wnl)[e4] = acc;
    }

    // xg (k=0:h, 1:xg1, 2:xg2) -> LDS, float4 (1536 of them; kb%4==0, no k-cross)
    for (int e4 = tid; e4 < 1536; e4 += 256) {
        int gi = e4 * 4;
        int bb = gi / 192, kb = gi % 192;
        int k = kb >> 6, i = kb & 63;
        const float* src = (k == 0) ? h : ((k == 1) ? xg1 : xg2);
        *(float4*)&xgl[bb][kb] = *(const float4*)&src[((size_t)(b0 + bb)*NN + n)*64 + i];
    }
    __syncthreads();

    int o = tid & 63, ty = tid >> 6;
    float bias = bN[n*64 + o];
    for (int bb = ty; bb < 32; bb += 4) {
        float acc = bias;
        for (int ki = 0; ki < 192; ki += 4) {
            float4 x4 = *(const float4*)&xgl[bb][ki];
            float w0 = Wnl[(ki+0)*64 + o];
            float w1 = Wnl[(ki+1)*64 + o];
            float w2 = Wnl[(ki+2)*64 + o];
            float w3 = Wnl[(ki+3)*64 + o];
            acc = fmaf(x4.x, w0, acc); acc = fmaf(x4.y, w1, acc);
            acc = fmaf(x4.z, w2, acc); acc = fmaf(x4.w, w3, acc);
        }
        h2h[((size_t)(b0 + bb)*NN + n)*64 + o] = (_Float16)acc;
    }
}

// out[r,j] = tanh( h2[r,:]·Wout[j,:] + bout[j] ), fp16 MFMA 16x16x32.
// SWAPPED operand order: mfma(b, a) puts out-row on lane&15 and out-col
// on quad*4+reg -> each lane owns 4 consecutive cols -> float4 NT stores.
__global__ __launch_bounds__(256) void k_out_proj_mfma(const _Float16* __restrict__ h2h,
                                                       const _Float16* __restrict__ Wh,
                                                       const float* __restrict__ bout,
                                                       float* __restrict__ out) {
    int tid  = threadIdx.x;
    int wave = tid >> 6, lane = tid & 63;
    int quad = lane >> 4, lr = lane & 15;
    int m0 = blockIdx.y*128 + (wave >> 1)*64;
    int n0 = blockIdx.x*128 + (wave & 1)*64;
    floatx4 acc[4][4] = {};   // [m-frag][n-frag]
    const _Float16* Aptr = h2h + (size_t)(m0 + lr)*64 + quad*8;
    const _Float16* Bptr = Wh  + (size_t)(n0 + lr)*64 + quad*8;
    #pragma unroll
    for (int ks = 0; ks < 2; ++ks) {
        f16x8 a[4], b[4];
        #pragma unroll
        for (int f = 0; f < 4; ++f) {
            a[f] = *(const f16x8*)(Aptr + (size_t)f*16*64 + ks*32);
            b[f] = *(const f16x8*)(Bptr + (size_t)f*16*64 + ks*32);
        }
        #pragma unroll
        for (int mf = 0; mf < 4; ++mf)
            #pragma unroll
            for (int nf = 0; nf < 4; ++nf)
                acc[mf][nf] = __builtin_amdgcn_mfma_f32_16x16x32_f16(b[nf], a[mf], acc[mf][nf], 0, 0, 0);
    }
    // Swapped D layout: lane&15 -> out row, quad*4+reg -> out col
    #pragma unroll
    for (int nf = 0; nf < 4; ++nf) {
        int c0 = n0 + nf*16 + quad*4;
        float4 bj = *(const float4*)&bout[c0];
        #pragma unroll
        for (int mf = 0; mf < 4; ++mf) {
            int row = m0 + mf*16 + lr;
            floatx4 v;
            v[0] = tanh_fast(acc[mf][nf][0] + bj.x);
            v[1] = tanh_fast(acc[mf][nf][1] + bj.y);
            v[2] = tanh_fast(acc[mf][nf][2] + bj.z);
            v[3] = tanh_fast(acc[mf][nf][3] + bj.w);
            __builtin_nontemporal_store(v, (floatx4*)&out[(size_t)row*JOUT + c0]);
        }
    }
}

extern "C" void kernel_launch(void* const* d_in, const int* in_sizes, int n_in,
                              void* d_out, int out_size, void* d_ws, size_t ws_size,
                              hipStream_t stream) {
    const float* z     = (const float*)d_in[0];   // [64,300,64]
    const float* Win   = (const float*)d_in[1];   // [64,64]
    const float* bin   = (const float*)d_in[2];   // [64]
    const float* Wout  = (const float*)d_in[3];   // [4096,64]
    const float* bout  = (const float*)d_in[4];   // [4096]
    const float* E     = (const float*)d_in[5];   // [300,10]
    const float* pool  = (const float*)d_in[6];   // [10,3,64,64]
    const float* bpool = (const float*)d_in[7];   // [10,64]
    float* out = (float*)d_out;                   // [64,300,64,64]

    float* ws  = (float*)d_ws;
    float* A   = ws;                 // 90,000
    float* bN  = A   + 90000;        // 19,200
    float* h   = bN  + 19200;        // 1,228,800
    float* xg1 = h   + 1228800;      // 1,228,800
    float* xg2 = xg1 + 1228800;      // 1,228,800
    _Float16* h2h   = (_Float16*)(xg2 + 1228800); // 1,228,800 fp16
    _Float16* Wouth = h2h + 1228800;              // 262,144 fp16 (total ~18.6 MB)

    k_pre      <<<1699, 256, 0, stream>>>(E, z, Win, bin, Wout, bpool,
                                          A, h, bN, Wouth);
    k_spatialA <<<dim3(15, BB), 256, 0, stream>>>(A, h, xg1);
    k_spatialB <<<dim3(15, BB), 256, 0, stream>>>(A, xg1, h, xg2);
    k_node_mm  <<<dim3(NN, 2), 256, 0, stream>>>(h, xg1, xg2, pool, E, bN, h2h);
    k_out_proj_mfma<<<dim3(JOUT/128, RTOT/128), 256, 0, stream>>>(h2h, Wouth, bout, out);
}